// Round 4
// baseline (423.891 us; speedup 1.0000x reference)
//
#include <hip/hip_runtime.h>
#include <hip/hip_bf16.h>
#include <stdint.h>

// Problem dims (fixed by setup_inputs)
#define B_N 4096
#define S_N 8192
#define KX  256
#define KY  128
// Tiling: 128x128 (batch x sample) tile per block, K fused (256 x + 128 y), BK=32
#define BM 128
#define BN 128

typedef __bf16 bf16x8 __attribute__((ext_vector_type(8)));
typedef float  f32x4  __attribute__((ext_vector_type(4)));

// ---- workspace byte offsets ----
#define OFF_XH   ((size_t)0)            // 4096*256*2 = 2 MB
#define OFF_YH   ((size_t)2097152)      // 4096*128*2 = 1 MB
#define OFF_SXH  ((size_t)3145728)      // 8192*256*2 = 4 MB
#define OFF_SYH  ((size_t)7340032)      // 8192*128*2 = 2 MB
#define OFF_NX   ((size_t)9437184)      // 4096 f32
#define OFF_NY   (OFF_NX + 16384)
#define OFF_NSX  (OFF_NY + 16384)       // 8192 f32
#define OFF_NSY  (OFF_NSX + 32768)
#define OFF_PART (OFF_NSY + 32768)      // [3][64][4096] float2 = 6.29 MB
#define OFF_BSUM (OFF_PART + (size_t)3*64*4096*2*4)   // 32 panel cnt + done + fsum

__device__ __forceinline__ void gl2lds16(const void* g, void* l) {
  // async global->LDS, 16B per lane; LDS dest = wave-uniform base + lane*16
  typedef const __attribute__((address_space(1))) unsigned int* gp_t;
  typedef __attribute__((address_space(3))) unsigned int* lp_t;
  __builtin_amdgcn_global_load_lds((gp_t)g, (lp_t)l, 16, 0, 0);
}

__device__ __forceinline__ unsigned short f2bf(float f) {
  unsigned u = __builtin_bit_cast(unsigned, f);
  return (unsigned short)((u + 0x7fffu + ((u >> 16) & 1u)) >> 16);
}

// ---- preprocessing: fp32 -> bf16 (round-nearest) + fp32 row norms ----
// Block 0 additionally zeroes the finalize counters (32 panel cnts, done, fsum).
__global__ __launch_bounds__(256) void conv_all(const float* __restrict__ x,
                                                const float* __restrict__ y,
                                                const float* __restrict__ xs,
                                                const float* __restrict__ ys,
                                                char* __restrict__ ws) {
  int b    = blockIdx.x;
  int wave = threadIdx.x >> 6;
  int lane = threadIdx.x & 63;
  if (b == 0 && threadIdx.x < 34) ((unsigned*)(ws + OFF_BSUM))[threadIdx.x] = 0u;
  const float* src; unsigned short* hi; float* nrm;
  int K, row;
  if (b < 1024) {
    src = x;  hi = (unsigned short*)(ws + OFF_XH);
    nrm = (float*)(ws + OFF_NX); K = 256; row = b * 4 + wave;
  } else if (b < 2048) {
    src = y;  hi = (unsigned short*)(ws + OFF_YH);
    nrm = (float*)(ws + OFF_NY); K = 128; row = (b - 1024) * 4 + wave;
  } else if (b < 4096) {
    src = xs; hi = (unsigned short*)(ws + OFF_SXH);
    nrm = (float*)(ws + OFF_NSX); K = 256; row = (b - 2048) * 4 + wave;
  } else {
    src = ys; hi = (unsigned short*)(ws + OFF_SYH);
    nrm = (float*)(ws + OFF_NSY); K = 128; row = (b - 4096) * 4 + wave;
  }
  float acc = 0.f;
  if (K == 256) {
    float4 v = ((const float4*)(src + (size_t)row * 256))[lane];
    float vv[4] = {v.x, v.y, v.z, v.w};
    ushort4 h4;
    unsigned short* hp = (unsigned short*)&h4;
    #pragma unroll
    for (int k = 0; k < 4; ++k) {
      hp[k] = f2bf(vv[k]);
      acc = fmaf(vv[k], vv[k], acc);
    }
    ((ushort4*)(hi + (size_t)row * 256))[lane] = h4;
  } else {
    float2 v = ((const float2*)(src + (size_t)row * 128))[lane];
    float vv[2] = {v.x, v.y};
    ushort2 h2;
    unsigned short* hp = (unsigned short*)&h2;
    #pragma unroll
    for (int k = 0; k < 2; ++k) {
      hp[k] = f2bf(vv[k]);
      acc = fmaf(vv[k], vv[k], acc);
    }
    ((ushort2*)(hi + (size_t)row * 128))[lane] = h2;
  }
  #pragma unroll
  for (int o = 32; o > 0; o >>= 1) acc += __shfl_down(acc, o);
  if (lane == 0) nrm[row] = acc;
}

// ---- main: fused dual-GEMM (x:K=256, y:K=128) + max-first lse + finalize ----
// 512 threads = 8 waves in 4x2: wave (wm,wn) owns rows wm*32+[0,32), cols wn*64+[0,64).
// A-operand: DIRECT global->VGPR (prefetched 1 chunk ahead; L1 absorbs the wn-pair
// redundancy, L2 slice 8KB/block/chunk). Only B goes through LDS: 4 buffers x 8KB.
// One s_barrier per chunk; explicit vmcnt is a conservative B-certify (the compiler's
// mandatory A-use vmcnt retires the same-chunk B-stage one iter earlier anyway).
// Order within iter pinned by "memory" fences: ds_read B(kc) | loadA(kc+1) | stageB(kc+3).
// Finalize (fin1+fin2 fused): last block per bm_t panel (device-scope atomic counter)
// lse-merges the 64 sn partials for its 128 rows; last panel writes out.
__global__ __launch_bounds__(512, 4) void mie_main(char* __restrict__ ws,
                                                   float* __restrict__ part,
                                                   float* __restrict__ out) {
  __shared__ __align__(16) char smem[49152];
  __shared__ int lastFlag;

  const int tid  = threadIdx.x;
  const int lane = tid & 63;
  const int wave = tid >> 6;
  const int c    = lane & 15;
  const int q    = lane >> 4;
  const int wm   = wave >> 1;   // 0..3
  const int wn   = wave & 1;    // 0..1

  const int b     = blockIdx.x;
  const int xcd   = b & 7;
  const int w     = b >> 3;              // 0..255
  const int bm_t  = w & 31;              // fast: A streams, stays L2-resident
  const int sn_t  = xcd * 8 + (w >> 5);  // 0..63
  const int bm0   = bm_t * BM;
  const int sn0   = sn_t * BN;

  const char* xh  = ws + OFF_XH;
  const char* yh  = ws + OFF_YH;
  const char* sxh = ws + OFF_SXH;
  const char* syh = ws + OFF_SYH;
  const float* nx  = (const float*)(ws + OFF_NX);
  const float* ny  = (const float*)(ws + OFF_NY);
  const float* nsx = (const float*)(ws + OFF_NSX);
  const float* nsy = (const float*)(ws + OFF_NSY);
  unsigned* cnt_panel = (unsigned*)(ws + OFF_BSUM);   // [32]
  unsigned* done      = cnt_panel + 32;
  float*    fsum      = (float*)(cnt_panel + 33);

  // B staging: thread tid carries granule g of row r.
  const int r  = tid >> 2;
  const int sg = (tid & 3) ^ ((r >> 1) & 3);
  const char* bXp = sxh + (size_t)(sn0 + r) * 512 + sg * 16;
  const char* bYp = syh + (size_t)(sn0 + r) * 256 + sg * 16;
  char* sdst = smem + wave * 1024;   // + buf*8192; gl2lds adds lane*16

  // A fragment global bases: lane (c,q) reads row (bm0+wm*32+i*16+c), bytes kc*64+q*16.
  const char* aXb = xh + (size_t)(bm0 + wm * 32 + c) * 512 + q * 16;
  const char* aYb = yh + (size_t)(bm0 + wm * 32 + c) * 256 + q * 16;

  // B fragment LDS offsets (row stride 64 B, swizzled slot)
  const int slot  = (q ^ ((c >> 1) & 3)) * 16;
  const int boff0 = (wn * 64 +  0 + c) * 64 + slot;
  const int boff1 = (wn * 64 + 16 + c) * 64 + slot;
  const int boff2 = (wn * 64 + 32 + c) * 64 + slot;
  const int boff3 = (wn * 64 + 48 + c) * 64 + slot;

  f32x4 accx[2][4], accy[2][4];
  #pragma unroll
  for (int i = 0; i < 2; ++i)
    #pragma unroll
    for (int j = 0; j < 4; ++j) {
      accx[i][j] = (f32x4){0.f,0.f,0.f,0.f};
      accy[i][j] = (f32x4){0.f,0.f,0.f,0.f};
    }

  bf16x8 AH[2][2];   // [chunk parity][i]

#define LOADA(kc, P) do {                                                   \
    if ((kc) < 8) {                                                         \
      AH[P][0] = *(const bf16x8*)(aXb + (kc) * 64);                         \
      AH[P][1] = *(const bf16x8*)(aXb + 8192 + (kc) * 64);                  \
    } else {                                                                \
      AH[P][0] = *(const bf16x8*)(aYb + ((kc) - 8) * 64);                   \
      AH[P][1] = *(const bf16x8*)(aYb + 4096 + ((kc) - 8) * 64);            \
    }                                                                       \
  } while (0)

#define STAGEB(kc) do {                                                     \
    const char* _sb = ((kc) < 8) ? (bXp + (kc) * 64) : (bYp + ((kc) - 8) * 64); \
    gl2lds16(_sb, sdst + ((kc) & 3) * 8192);                                \
  } while (0)

#define MFMA8(ACC, A0, A1, B0, B1, B2, B3) do {                                   \
    ACC[0][0] = __builtin_amdgcn_mfma_f32_16x16x32_bf16(A0, B0, ACC[0][0], 0,0,0); \
    ACC[0][1] = __builtin_amdgcn_mfma_f32_16x16x32_bf16(A0, B1, ACC[0][1], 0,0,0); \
    ACC[0][2] = __builtin_amdgcn_mfma_f32_16x16x32_bf16(A0, B2, ACC[0][2], 0,0,0); \
    ACC[0][3] = __builtin_amdgcn_mfma_f32_16x16x32_bf16(A0, B3, ACC[0][3], 0,0,0); \
    ACC[1][0] = __builtin_amdgcn_mfma_f32_16x16x32_bf16(A1, B0, ACC[1][0], 0,0,0); \
    ACC[1][1] = __builtin_amdgcn_mfma_f32_16x16x32_bf16(A1, B1, ACC[1][1], 0,0,0); \
    ACC[1][2] = __builtin_amdgcn_mfma_f32_16x16x32_bf16(A1, B2, ACC[1][2], 0,0,0); \
    ACC[1][3] = __builtin_amdgcn_mfma_f32_16x16x32_bf16(A1, B3, ACC[1][3], 0,0,0); \
  } while (0)

  // vm = conservative certify of B(kc) before the barrier (count of vmem ops
  // provably newer than B(kc) given the fenced per-iter order A-loads|B-stage).
#define ITER(kc, vm, ACC) do {                                              \
    asm volatile("s_waitcnt vmcnt(" #vm ")" ::: "memory");                  \
    __builtin_amdgcn_s_barrier();                                           \
    asm volatile("" ::: "memory");                                          \
    const char* _b = smem + ((kc) & 3) * 8192;                              \
    bf16x8 _B0 = *(const bf16x8*)(_b + boff0);                              \
    bf16x8 _B1 = *(const bf16x8*)(_b + boff1);                              \
    bf16x8 _B2 = *(const bf16x8*)(_b + boff2);                              \
    bf16x8 _B3 = *(const bf16x8*)(_b + boff3);                              \
    if ((kc) + 1 < 12) LOADA((kc) + 1, (((kc) + 1) & 1));                   \
    asm volatile("" ::: "memory");                                          \
    if ((kc) + 3 < 12) STAGEB((kc) + 3);                                    \
    __builtin_amdgcn_s_setprio(1);                                          \
    MFMA8(ACC, AH[(kc) & 1][0], AH[(kc) & 1][1], _B0, _B1, _B2, _B3);       \
    __builtin_amdgcn_s_setprio(0);                                          \
  } while (0)

  // prologue: A(0) first (so B0..B2 are newer), then 3 B-stages in flight
  LOADA(0, 0);
  asm volatile("" ::: "memory");
  STAGEB(0); STAGEB(1); STAGEB(2);

  ITER(0, 2, accx);  ITER(1, 4, accx);  ITER(2, 6, accx);  ITER(3, 6, accx);
  ITER(4, 6, accx);  ITER(5, 6, accx);  ITER(6, 6, accx);  ITER(7, 6, accx);
  ITER(8, 6, accy);  ITER(9, 6, accy);  ITER(10, 5, accy); ITER(11, 4, accy);

#undef ITER
#undef MFMA8
#undef STAGEB
#undef LOADA

  // B-buffers overlap the epilogue LDS table now -> fence all waves' reads first.
  __syncthreads();

  // ---- epilogue: v = acc - 0.5*(||a||^2 + ||b||^2); max-first lse ----
  float hxv[2][4], hyv[2][4];
  #pragma unroll
  for (int i = 0; i < 2; ++i)
    #pragma unroll
    for (int rr4 = 0; rr4 < 4; ++rr4) {
      int rr = bm0 + wm * 32 + i * 16 + q * 4 + rr4;
      hxv[i][rr4] = -0.5f * nx[rr];
      hyv[i][rr4] = -0.5f * ny[rr];
    }
  float hsxv[4], hsyv[4];
  #pragma unroll
  for (int j = 0; j < 4; ++j) {
    int cc = sn0 + wn * 64 + j * 16 + c;
    hsxv[j] = -0.5f * nsx[cc];
    hsyv[j] = -0.5f * nsy[cc];
  }

  float2* xch2 = (float2*)smem;   // [3][128][16] float2 = 48 KB
  #pragma unroll
  for (int i = 0; i < 2; ++i) {
    #pragma unroll
    for (int rr4 = 0; rr4 < 4; ++rr4) {
      float vx[4], vy[4];
      #pragma unroll
      for (int j = 0; j < 4; ++j) {
        vx[j] = accx[i][j][rr4] + hxv[i][rr4] + hsxv[j];
        vy[j] = accy[i][j][rr4] + hyv[i][rr4] + hsyv[j];
      }
      int rl = wm * 32 + i * 16 + q * 4 + rr4;
      #pragma unroll
      for (int st = 0; st < 3; ++st) {
        float v0 = (st == 0) ? vx[0] + vy[0] : (st == 1 ? vx[0] : vy[0]);
        float v1 = (st == 0) ? vx[1] + vy[1] : (st == 1 ? vx[1] : vy[1]);
        float v2 = (st == 0) ? vx[2] + vy[2] : (st == 1 ? vx[2] : vy[2]);
        float v3 = (st == 0) ? vx[3] + vy[3] : (st == 1 ? vx[3] : vy[3]);
        float m = fmaxf(fmaxf(v0, v1), fmaxf(v2, v3));
        float s = __expf(v0 - m) + __expf(v1 - m) + __expf(v2 - m) + __expf(v3 - m);
        // merge lanes c and c^8 (both halves compute identical result)
        float mo = __shfl_xor(m, 8);
        float so = __shfl_xor(s, 8);
        float nm = fmaxf(m, mo);
        float ns = s * __expf(m - nm) + so * __expf(mo - nm);
        if (c < 8) xch2[(st * 128 + rl) * 16 + wn * 8 + c] = (float2){nm, ns};
      }
    }
  }
  __syncthreads();

  // merge the 16 lane-partials per (stream,row); write coalesced [3][64][4096]
  if (tid < 384) {
    int st = tid >> 7;
    int rl = tid & 127;
    const float2* row = xch2 + (st * 128 + rl) * 16;
    int p0 = rl & 15;                 // rotate read order: breaks bank conflict
    float2 a = row[p0];
    float m = a.x, s = a.y;
    #pragma unroll
    for (int p = 1; p < 16; ++p) {
      float2 e = row[(p0 + p) & 15];
      float nm = fmaxf(m, e.x);
      s = s * __expf(m - nm) + e.y * __expf(e.x - nm);
      m = nm;
    }
    size_t idx = ((size_t)st * 64 + sn_t) * B_N + (bm0 + rl);
    ((float2*)part)[idx] = (float2){m, s};
  }

  // ---- fused finalize: last block of this bm_t panel merges all 64 sn partials ----
  __threadfence();          // release part[] device-wide
  __syncthreads();          // all threads' part writes precede the count
  if (tid == 0) {
    unsigned old = atomicAdd(cnt_panel + bm_t, 1u);
    lastFlag = (old == 63u) ? 1 : 0;
  }
  __syncthreads();
  if (lastFlag) {
    __threadfence();        // acquire other blocks' part writes
    float* vtab = (float*)smem;        // [3][128] + 2 scratch
    if (tid < 384) {
      int st = tid >> 7;
      int rl = tid & 127;
      const float2* pp = (const float2*)part + (size_t)st * 64 * B_N + (bm0 + rl);
      float m = -__builtin_inff(), s = 0.f;
      #pragma unroll 8
      for (int p = 0; p < 64; ++p) {
        float2 e = pp[(size_t)p * B_N];
        float nm = fmaxf(m, e.x);
        s = s * __expf(m - nm) + e.y * __expf(e.x - nm);
        m = nm;
      }
      vtab[st * 128 + rl] = m + __logf(s);
    }
    __syncthreads();
    if (tid < 128) {
      float local = vtab[tid] - vtab[128 + tid] - vtab[256 + tid];
      #pragma unroll
      for (int o = 32; o > 0; o >>= 1) local += __shfl_down(local, o);
      if ((tid & 63) == 0) vtab[384 + (tid >> 6)] = local;
    }
    __syncthreads();
    if (tid == 0) {
      float ps = vtab[384] + vtab[385];
      atomicAdd(fsum, ps);
      __threadfence();
      unsigned od = atomicAdd(done, 1u);
      if (od == 31u) {
        __threadfence();
        float tot = atomicAdd(fsum, 0.0f);   // atomic read of the completed sum
        out[0] = tot * (1.0f / (float)B_N);
      }
    }
  }
}

extern "C" void kernel_launch(void* const* d_in, const int* in_sizes, int n_in,
                              void* d_out, int out_size, void* d_ws, size_t ws_size,
                              hipStream_t stream) {
  (void)in_sizes; (void)n_in; (void)out_size; (void)ws_size;
  const float* x  = (const float*)d_in[0];
  const float* y  = (const float*)d_in[1];
  const float* xs = (const float*)d_in[2];
  const float* ys = (const float*)d_in[3];
  char* ws = (char*)d_ws;

  conv_all<<<6144, 256, 0, stream>>>(x, y, xs, ys, ws);
  mie_main<<<2048, 512, 0, stream>>>(ws, (float*)(ws + OFF_PART), (float*)d_out);
}

// Round 5
// 144.531 us; speedup vs baseline: 2.9329x; 2.9329x over previous
//
#include <hip/hip_runtime.h>
#include <hip/hip_bf16.h>
#include <stdint.h>

// Problem dims (fixed by setup_inputs)
#define B_N 4096
#define S_N 8192
#define KX  256
#define KY  128
// Tiling: 128x128 (batch x sample) tile per block, K fused (256 x + 128 y), BK=32
#define BM 128
#define BN 128

typedef __bf16 bf16x8 __attribute__((ext_vector_type(8)));
typedef float  f32x4  __attribute__((ext_vector_type(4)));

// ---- workspace byte offsets ----
#define OFF_XH   ((size_t)0)            // 4096*256*2 = 2 MB
#define OFF_YH   ((size_t)2097152)      // 4096*128*2 = 1 MB
#define OFF_SXH  ((size_t)3145728)      // 8192*256*2 = 4 MB
#define OFF_SYH  ((size_t)7340032)      // 8192*128*2 = 2 MB
#define OFF_NX   ((size_t)9437184)      // 4096 f32
#define OFF_NY   (OFF_NX + 16384)
#define OFF_NSX  (OFF_NY + 16384)       // 8192 f32
#define OFF_NSY  (OFF_NSX + 32768)
#define OFF_PART (OFF_NSY + 32768)      // [3][64][4096] float2 = 6.29 MB
#define OFF_BSUM (OFF_PART + (size_t)3*64*4096*2*4)   // 64 f32

__device__ __forceinline__ void gl2lds16(const void* g, void* l) {
  // async global->LDS, 16B per lane; LDS dest = wave-uniform base + lane*16
  typedef const __attribute__((address_space(1))) unsigned int* gp_t;
  typedef __attribute__((address_space(3))) unsigned int* lp_t;
  __builtin_amdgcn_global_load_lds((gp_t)g, (lp_t)l, 16, 0, 0);
}

__device__ __forceinline__ unsigned short f2bf(float f) {
  unsigned u = __builtin_bit_cast(unsigned, f);
  return (unsigned short)((u + 0x7fffu + ((u >> 16) & 1u)) >> 16);
}

// ---- preprocessing: fp32 -> bf16 (round-nearest) + fp32 row norms ----
__global__ __launch_bounds__(256) void conv_all(const float* __restrict__ x,
                                                const float* __restrict__ y,
                                                const float* __restrict__ xs,
                                                const float* __restrict__ ys,
                                                char* __restrict__ ws) {
  int b    = blockIdx.x;
  int wave = threadIdx.x >> 6;
  int lane = threadIdx.x & 63;
  const float* src; unsigned short* hi; float* nrm;
  int K, row;
  if (b < 1024) {
    src = x;  hi = (unsigned short*)(ws + OFF_XH);
    nrm = (float*)(ws + OFF_NX); K = 256; row = b * 4 + wave;
  } else if (b < 2048) {
    src = y;  hi = (unsigned short*)(ws + OFF_YH);
    nrm = (float*)(ws + OFF_NY); K = 128; row = (b - 1024) * 4 + wave;
  } else if (b < 4096) {
    src = xs; hi = (unsigned short*)(ws + OFF_SXH);
    nrm = (float*)(ws + OFF_NSX); K = 256; row = (b - 2048) * 4 + wave;
  } else {
    src = ys; hi = (unsigned short*)(ws + OFF_SYH);
    nrm = (float*)(ws + OFF_NSY); K = 128; row = (b - 4096) * 4 + wave;
  }
  float acc = 0.f;
  if (K == 256) {
    float4 v = ((const float4*)(src + (size_t)row * 256))[lane];
    float vv[4] = {v.x, v.y, v.z, v.w};
    ushort4 h4;
    unsigned short* hp = (unsigned short*)&h4;
    #pragma unroll
    for (int k = 0; k < 4; ++k) {
      hp[k] = f2bf(vv[k]);
      acc = fmaf(vv[k], vv[k], acc);
    }
    ((ushort4*)(hi + (size_t)row * 256))[lane] = h4;
  } else {
    float2 v = ((const float2*)(src + (size_t)row * 128))[lane];
    float vv[2] = {v.x, v.y};
    ushort2 h2;
    unsigned short* hp = (unsigned short*)&h2;
    #pragma unroll
    for (int k = 0; k < 2; ++k) {
      hp[k] = f2bf(vv[k]);
      acc = fmaf(vv[k], vv[k], acc);
    }
    ((ushort2*)(hi + (size_t)row * 128))[lane] = h2;
  }
  #pragma unroll
  for (int o = 32; o > 0; o >>= 1) acc += __shfl_down(acc, o);
  if (lane == 0) nrm[row] = acc;
}

// ---- main: fused dual-GEMM (x:K=256, y:K=128) + max-first lse epilogue ----
// 512 threads = 8 waves in 4x2: wave (wm,wn) owns rows wm*32+[0,32), cols wn*64+[0,64).
// A-operand: DIRECT global->VGPR (prefetched 1 chunk ahead; L1/L2 absorb the wn-pair
// redundancy). Only B goes through LDS: 4 buffers x 8KB = 32 KB.
// One s_barrier per chunk; explicit vmcnt certifies B(kc)'s stage conservatively
// (compiler inserts its own waits for the A-register loads).
// NO device-scope fences/atomics in this kernel (R4 lesson: __threadfence() per
// block = L2 writeback storms on non-coherent per-XCD L2s -> 6x collapse).
// Chunk layout: 128 rows x 64 B; 16B granule g stored at slot g ^ ((r>>1)&3).
// XCD swizzle: xcd=b&7; bm fast-varying so each XCD's A set (3 MB) + B stay L2-hot.
__global__ __launch_bounds__(512, 4) void mie_main(const char* __restrict__ ws,
                                                   float* __restrict__ part) {
  __shared__ __align__(16) char smem[49152];

  const int tid  = threadIdx.x;
  const int lane = tid & 63;
  const int wave = tid >> 6;
  const int c    = lane & 15;
  const int q    = lane >> 4;
  const int wm   = wave >> 1;   // 0..3
  const int wn   = wave & 1;    // 0..1

  const int b     = blockIdx.x;
  const int xcd   = b & 7;
  const int w     = b >> 3;              // 0..255
  const int bm_t  = w & 31;              // fast: A streams, stays L2-resident
  const int sn_t  = xcd * 8 + (w >> 5);  // 0..63
  const int bm0   = bm_t * BM;
  const int sn0   = sn_t * BN;

  const char* xh  = ws + OFF_XH;
  const char* yh  = ws + OFF_YH;
  const char* sxh = ws + OFF_SXH;
  const char* syh = ws + OFF_SYH;
  const float* nx  = (const float*)(ws + OFF_NX);
  const float* ny  = (const float*)(ws + OFF_NY);
  const float* nsx = (const float*)(ws + OFF_NSX);
  const float* nsy = (const float*)(ws + OFF_NSY);

  // B staging: thread tid carries granule g of row r.
  const int r  = tid >> 2;
  const int sg = (tid & 3) ^ ((r >> 1) & 3);
  const char* bXp = sxh + (size_t)(sn0 + r) * 512 + sg * 16;
  const char* bYp = syh + (size_t)(sn0 + r) * 256 + sg * 16;
  char* sdst = smem + wave * 1024;   // + buf*8192; gl2lds adds lane*16

  // A fragment global bases: lane (c,q) reads row (bm0+wm*32+i*16+c), bytes kc*64+q*16.
  const char* aXb = xh + (size_t)(bm0 + wm * 32 + c) * 512 + q * 16;
  const char* aYb = yh + (size_t)(bm0 + wm * 32 + c) * 256 + q * 16;

  // B fragment LDS offsets (row stride 64 B, swizzled slot)
  const int slot  = (q ^ ((c >> 1) & 3)) * 16;
  const int boff0 = (wn * 64 +  0 + c) * 64 + slot;
  const int boff1 = (wn * 64 + 16 + c) * 64 + slot;
  const int boff2 = (wn * 64 + 32 + c) * 64 + slot;
  const int boff3 = (wn * 64 + 48 + c) * 64 + slot;

  f32x4 accx[2][4], accy[2][4];
  #pragma unroll
  for (int i = 0; i < 2; ++i)
    #pragma unroll
    for (int j = 0; j < 4; ++j) {
      accx[i][j] = (f32x4){0.f,0.f,0.f,0.f};
      accy[i][j] = (f32x4){0.f,0.f,0.f,0.f};
    }

  bf16x8 AH[2][2];   // [chunk parity][i] -- all indices compile-time constant

#define LOADA(kc, P) do {                                                   \
    if ((kc) < 8) {                                                         \
      AH[P][0] = *(const bf16x8*)(aXb + (kc) * 64);                         \
      AH[P][1] = *(const bf16x8*)(aXb + 8192 + (kc) * 64);                  \
    } else {                                                                \
      AH[P][0] = *(const bf16x8*)(aYb + ((kc) - 8) * 64);                   \
      AH[P][1] = *(const bf16x8*)(aYb + 4096 + ((kc) - 8) * 64);            \
    }                                                                       \
  } while (0)

#define STAGEB(kc) do {                                                     \
    const char* _sb = ((kc) < 8) ? (bXp + (kc) * 64) : (bYp + ((kc) - 8) * 64); \
    gl2lds16(_sb, sdst + ((kc) & 3) * 8192);                                \
  } while (0)

#define MFMA8(ACC, A0, A1, B0, B1, B2, B3) do {                                   \
    ACC[0][0] = __builtin_amdgcn_mfma_f32_16x16x32_bf16(A0, B0, ACC[0][0], 0,0,0); \
    ACC[0][1] = __builtin_amdgcn_mfma_f32_16x16x32_bf16(A0, B1, ACC[0][1], 0,0,0); \
    ACC[0][2] = __builtin_amdgcn_mfma_f32_16x16x32_bf16(A0, B2, ACC[0][2], 0,0,0); \
    ACC[0][3] = __builtin_amdgcn_mfma_f32_16x16x32_bf16(A0, B3, ACC[0][3], 0,0,0); \
    ACC[1][0] = __builtin_amdgcn_mfma_f32_16x16x32_bf16(A1, B0, ACC[1][0], 0,0,0); \
    ACC[1][1] = __builtin_amdgcn_mfma_f32_16x16x32_bf16(A1, B1, ACC[1][1], 0,0,0); \
    ACC[1][2] = __builtin_amdgcn_mfma_f32_16x16x32_bf16(A1, B2, ACC[1][2], 0,0,0); \
    ACC[1][3] = __builtin_amdgcn_mfma_f32_16x16x32_bf16(A1, B3, ACC[1][3], 0,0,0); \
  } while (0)

  // vm = conservative certify of B(kc)'s stage before the barrier: count of vmem
  // ops provably newer than STAGEB(kc) assuming NO compiler waits (worst case).
#define ITER(kc, vm, ACC) do {                                              \
    asm volatile("s_waitcnt vmcnt(" #vm ")" ::: "memory");                  \
    __builtin_amdgcn_s_barrier();                                           \
    asm volatile("" ::: "memory");                                          \
    const char* _b = smem + ((kc) & 3) * 8192;                              \
    bf16x8 _B0 = *(const bf16x8*)(_b + boff0);                              \
    bf16x8 _B1 = *(const bf16x8*)(_b + boff1);                              \
    bf16x8 _B2 = *(const bf16x8*)(_b + boff2);                              \
    bf16x8 _B3 = *(const bf16x8*)(_b + boff3);                              \
    if ((kc) + 1 < 12) LOADA((kc) + 1, (((kc) + 1) & 1));                   \
    asm volatile("" ::: "memory");                                          \
    if ((kc) + 3 < 12) STAGEB((kc) + 3);                                    \
    __builtin_amdgcn_s_setprio(1);                                          \
    MFMA8(ACC, AH[(kc) & 1][0], AH[(kc) & 1][1], _B0, _B1, _B2, _B3);       \
    __builtin_amdgcn_s_setprio(0);                                          \
  } while (0)

  // prologue: A(0) first (so B0..B2 are newer), then 3 B-stages in flight
  LOADA(0, 0);
  asm volatile("" ::: "memory");
  STAGEB(0); STAGEB(1); STAGEB(2);

  ITER(0, 2, accx);  ITER(1, 4, accx);  ITER(2, 6, accx);  ITER(3, 6, accx);
  ITER(4, 6, accx);  ITER(5, 6, accx);  ITER(6, 6, accx);  ITER(7, 6, accx);
  ITER(8, 6, accy);  ITER(9, 6, accy);  ITER(10, 5, accy); ITER(11, 4, accy);

#undef ITER
#undef MFMA8
#undef STAGEB
#undef LOADA

  // B-buffers (32 KB) overlap the 48 KB epilogue LDS table -> fence reads first.
  __syncthreads();

  // ---- epilogue: v = acc - 0.5*(||a||^2 + ||b||^2); max-first lse ----
  float hxv[2][4], hyv[2][4];
  #pragma unroll
  for (int i = 0; i < 2; ++i)
    #pragma unroll
    for (int rr4 = 0; rr4 < 4; ++rr4) {
      int rr = bm0 + wm * 32 + i * 16 + q * 4 + rr4;
      hxv[i][rr4] = -0.5f * nx[rr];
      hyv[i][rr4] = -0.5f * ny[rr];
    }
  float hsxv[4], hsyv[4];
  #pragma unroll
  for (int j = 0; j < 4; ++j) {
    int cc = sn0 + wn * 64 + j * 16 + c;
    hsxv[j] = -0.5f * nsx[cc];
    hsyv[j] = -0.5f * nsy[cc];
  }

  float2* xch2 = (float2*)smem;   // [3][128][16] float2 = 48 KB
  #pragma unroll
  for (int i = 0; i < 2; ++i) {
    #pragma unroll
    for (int rr4 = 0; rr4 < 4; ++rr4) {
      float vx[4], vy[4];
      #pragma unroll
      for (int j = 0; j < 4; ++j) {
        vx[j] = accx[i][j][rr4] + hxv[i][rr4] + hsxv[j];
        vy[j] = accy[i][j][rr4] + hyv[i][rr4] + hsyv[j];
      }
      int rl = wm * 32 + i * 16 + q * 4 + rr4;
      #pragma unroll
      for (int st = 0; st < 3; ++st) {
        float v0 = (st == 0) ? vx[0] + vy[0] : (st == 1 ? vx[0] : vy[0]);
        float v1 = (st == 0) ? vx[1] + vy[1] : (st == 1 ? vx[1] : vy[1]);
        float v2 = (st == 0) ? vx[2] + vy[2] : (st == 1 ? vx[2] : vy[2]);
        float v3 = (st == 0) ? vx[3] + vy[3] : (st == 1 ? vx[3] : vy[3]);
        float m = fmaxf(fmaxf(v0, v1), fmaxf(v2, v3));
        float s = __expf(v0 - m) + __expf(v1 - m) + __expf(v2 - m) + __expf(v3 - m);
        // merge lanes c and c^8 (both halves compute identical result)
        float mo = __shfl_xor(m, 8);
        float so = __shfl_xor(s, 8);
        float nm = fmaxf(m, mo);
        float ns = s * __expf(m - nm) + so * __expf(mo - nm);
        if (c < 8) xch2[(st * 128 + rl) * 16 + wn * 8 + c] = (float2){nm, ns};
      }
    }
  }
  __syncthreads();

  // merge the 16 lane-partials per (stream,row); write coalesced [3][64][4096]
  if (tid < 384) {
    int st = tid >> 7;
    int rl = tid & 127;
    const float2* row = xch2 + (st * 128 + rl) * 16;
    int p0 = rl & 15;                 // rotate read order: breaks bank conflict
    float2 a = row[p0];
    float m = a.x, s = a.y;
    #pragma unroll
    for (int p = 1; p < 16; ++p) {
      float2 e = row[(p0 + p) & 15];
      float nm = fmaxf(m, e.x);
      s = s * __expf(m - nm) + e.y * __expf(e.x - nm);
      m = nm;
    }
    size_t idx = ((size_t)st * 64 + sn_t) * B_N + (bm0 + rl);
    ((float2*)part)[idx] = (float2){m, s};
  }
}

// ---- finalize stage 1: per-row lse over 64 partials, 4 waves split p-range ----
__global__ __launch_bounds__(256) void fin1(const float* __restrict__ part,
                                            float* __restrict__ bsum) {
  __shared__ float2 lds[3][4][64];
  int tid  = threadIdx.x;
  int wave = tid >> 6;
  int lane = tid & 63;
  int row  = blockIdx.x * 64 + lane;
  #pragma unroll
  for (int j = 0; j < 3; ++j) {
    float m = -__builtin_inff(), s = 0.f;
    #pragma unroll
    for (int pp = 0; pp < 16; ++pp) {
      int p = wave * 16 + pp;
      float2 a = ((const float2*)part)[((size_t)j * 64 + p) * B_N + row];
      float nm = fmaxf(m, a.x);
      s = s * __expf(m - nm) + a.y * __expf(a.x - nm);
      m = nm;
    }
    lds[j][wave][lane] = (float2){m, s};
  }
  __syncthreads();
  if (wave == 0) {
    float v[3];
    #pragma unroll
    for (int j = 0; j < 3; ++j) {
      float m = -__builtin_inff(), s = 0.f;
      #pragma unroll
      for (int u = 0; u < 4; ++u) {
        float2 a = lds[j][u][lane];
        float nm = fmaxf(m, a.x);
        s = s * __expf(m - nm) + a.y * __expf(a.x - nm);
        m = nm;
      }
      v[j] = m + __logf(s);
    }
    float local = v[0] - v[1] - v[2];
    #pragma unroll
    for (int o = 32; o > 0; o >>= 1) local += __shfl_down(local, o);
    if (lane == 0) bsum[blockIdx.x] = local;
  }
}

// ---- finalize stage 2: mean over 4096 rows (64 block sums) ----
__global__ void fin2(const float* __restrict__ bsum, float* __restrict__ out) {
  int t = threadIdx.x;
  float a = bsum[t];
  #pragma unroll
  for (int o = 32; o > 0; o >>= 1) a += __shfl_down(a, o);
  if (t == 0) out[0] = a * (1.0f / (float)B_N);
}

extern "C" void kernel_launch(void* const* d_in, const int* in_sizes, int n_in,
                              void* d_out, int out_size, void* d_ws, size_t ws_size,
                              hipStream_t stream) {
  (void)in_sizes; (void)n_in; (void)out_size; (void)ws_size;
  const float* x  = (const float*)d_in[0];
  const float* y  = (const float*)d_in[1];
  const float* xs = (const float*)d_in[2];
  const float* ys = (const float*)d_in[3];
  char* ws = (char*)d_ws;

  conv_all<<<6144, 256, 0, stream>>>(x, y, xs, ys, ws);
  mie_main<<<2048, 512, 0, stream>>>(ws, (float*)(ws + OFF_PART));
  fin1<<<B_N / 64, 256, 0, stream>>>((const float*)(ws + OFF_PART), (float*)(ws + OFF_BSUM));
  fin2<<<1, 64, 0, stream>>>((const float*)(ws + OFF_BSUM), (float*)d_out);
}

// Round 6
// 131.291 us; speedup vs baseline: 3.2286x; 1.1008x over previous
//
#include <hip/hip_runtime.h>
#include <hip/hip_bf16.h>
#include <stdint.h>

// Problem dims (fixed by setup_inputs)
#define B_N 4096
#define S_N 8192
#define KX  256
#define KY  128
// Tiling: 128x128 (batch x sample) tile per block, K fused (256 x + 128 y), BK=32
#define BM 128
#define BN 128

typedef __bf16 bf16x8 __attribute__((ext_vector_type(8)));
typedef float  f32x4  __attribute__((ext_vector_type(4)));

// ---- workspace byte offsets ----
#define OFF_XH   ((size_t)0)            // 4096*256*2 = 2 MB
#define OFF_YH   ((size_t)2097152)      // 4096*128*2 = 1 MB
#define OFF_SXH  ((size_t)3145728)      // 8192*256*2 = 4 MB
#define OFF_SYH  ((size_t)7340032)      // 8192*128*2 = 2 MB
#define OFF_NX   ((size_t)9437184)      // 4096 f32
#define OFF_NY   (OFF_NX + 16384)
#define OFF_NSX  (OFF_NY + 16384)       // 8192 f32
#define OFF_NSY  (OFF_NSX + 32768)
#define OFF_PART (OFF_NSY + 32768)      // [3][64][4096] float2 = 6.29 MB
#define OFF_BSUM (OFF_PART + (size_t)3*64*4096*2*4)   // [0]=done u32, [1]=fsum f32

__device__ __forceinline__ void gl2lds16(const void* g, void* l) {
  // async global->LDS, 16B per lane; LDS dest = wave-uniform base + lane*16
  typedef const __attribute__((address_space(1))) unsigned int* gp_t;
  typedef __attribute__((address_space(3))) unsigned int* lp_t;
  __builtin_amdgcn_global_load_lds((gp_t)g, (lp_t)l, 16, 0, 0);
}

__device__ __forceinline__ unsigned short f2bf(float f) {
  unsigned u = __builtin_bit_cast(unsigned, f);
  return (unsigned short)((u + 0x7fffu + ((u >> 16) & 1u)) >> 16);
}

// ---- preprocessing: fp32 -> bf16 (round-nearest) + fp32 row norms ----
// Block 0 additionally zeroes the finalize sync cells (done, fsum).
__global__ __launch_bounds__(256) void conv_all(const float* __restrict__ x,
                                                const float* __restrict__ y,
                                                const float* __restrict__ xs,
                                                const float* __restrict__ ys,
                                                char* __restrict__ ws) {
  int b    = blockIdx.x;
  int wave = threadIdx.x >> 6;
  int lane = threadIdx.x & 63;
  if (b == 0 && threadIdx.x < 2) ((unsigned*)(ws + OFF_BSUM))[threadIdx.x] = 0u;
  const float* src; unsigned short* hi; float* nrm;
  int K, row;
  if (b < 1024) {
    src = x;  hi = (unsigned short*)(ws + OFF_XH);
    nrm = (float*)(ws + OFF_NX); K = 256; row = b * 4 + wave;
  } else if (b < 2048) {
    src = y;  hi = (unsigned short*)(ws + OFF_YH);
    nrm = (float*)(ws + OFF_NY); K = 128; row = (b - 1024) * 4 + wave;
  } else if (b < 4096) {
    src = xs; hi = (unsigned short*)(ws + OFF_SXH);
    nrm = (float*)(ws + OFF_NSX); K = 256; row = (b - 2048) * 4 + wave;
  } else {
    src = ys; hi = (unsigned short*)(ws + OFF_SYH);
    nrm = (float*)(ws + OFF_NSY); K = 128; row = (b - 4096) * 4 + wave;
  }
  float acc = 0.f;
  if (K == 256) {
    float4 v = ((const float4*)(src + (size_t)row * 256))[lane];
    float vv[4] = {v.x, v.y, v.z, v.w};
    ushort4 h4;
    unsigned short* hp = (unsigned short*)&h4;
    #pragma unroll
    for (int k = 0; k < 4; ++k) {
      hp[k] = f2bf(vv[k]);
      acc = fmaf(vv[k], vv[k], acc);
    }
    ((ushort4*)(hi + (size_t)row * 256))[lane] = h4;
  } else {
    float2 v = ((const float2*)(src + (size_t)row * 128))[lane];
    float vv[2] = {v.x, v.y};
    ushort2 h2;
    unsigned short* hp = (unsigned short*)&h2;
    #pragma unroll
    for (int k = 0; k < 2; ++k) {
      hp[k] = f2bf(vv[k]);
      acc = fmaf(vv[k], vv[k], acc);
    }
    ((ushort2*)(hi + (size_t)row * 128))[lane] = h2;
  }
  #pragma unroll
  for (int o = 32; o > 0; o >>= 1) acc += __shfl_down(acc, o);
  if (lane == 0) nrm[row] = acc;
}

// ---- main: fused dual-GEMM (x:K=256, y:K=128) + max-first lse epilogue ----
// 512 threads = 8 waves in 4x2: wave (wm,wn) owns rows wm*32+[0,32), cols wn*64+[0,64).
// R3-verified K-loop (61 us): both A and B staged via global_load_lds into 4x16KB
// LDS buffers (homogeneous vmcnt queue -- R5 lesson: mixing per-VGPR operand loads
// into the queue defeats the counted-vmcnt prefetch discipline).
// Per chunk kc: vmcnt(4) [certify stage(kc); stages kc+1,kc+2 in flight] ; s_barrier ;
// ds_read(kc) ; STAGE(kc+3) ; setprio(1) MFMA setprio(0).  One barrier per chunk.
// NO device-scope fences in this kernel (R4 lesson).
// Chunk layout: 128 rows x 64 B; 16B granule g stored at slot g ^ ((r>>1)&3).
// XCD swizzle: xcd=b&7; bm fast-varying so each XCD's A set (3 MB) + B stay L2-hot.
__global__ __launch_bounds__(512, 4) void mie_main(const char* __restrict__ ws,
                                                   float* __restrict__ part) {
  __shared__ __align__(16) char smem[65536];

  const int tid  = threadIdx.x;
  const int lane = tid & 63;
  const int wave = tid >> 6;
  const int c    = lane & 15;
  const int q    = lane >> 4;
  const int wm   = wave >> 1;   // 0..3
  const int wn   = wave & 1;    // 0..1

  const int b     = blockIdx.x;
  const int xcd   = b & 7;
  const int w     = b >> 3;              // 0..255
  const int bm_t  = w & 31;              // fast: A streams, stays L2-resident
  const int sn_t  = xcd * 8 + (w >> 5);  // 0..63
  const int bm0   = bm_t * BM;
  const int sn0   = sn_t * BN;

  const char* xh  = ws + OFF_XH;
  const char* yh  = ws + OFF_YH;
  const char* sxh = ws + OFF_SXH;
  const char* syh = ws + OFF_SYH;
  const float* nx  = (const float*)(ws + OFF_NX);
  const float* ny  = (const float*)(ws + OFF_NY);
  const float* nsx = (const float*)(ws + OFF_NSX);
  const float* nsy = (const float*)(ws + OFF_NSY);

  // staging: thread tid carries granule g of row r for both A and B sides.
  const int r  = tid >> 2;
  const int sg = (tid & 3) ^ ((r >> 1) & 3);
  const char* aXp = xh  + (size_t)(bm0 + r) * 512 + sg * 16;
  const char* aYp = yh  + (size_t)(bm0 + r) * 256 + sg * 16;
  const char* bXp = sxh + (size_t)(sn0 + r) * 512 + sg * 16;
  const char* bYp = syh + (size_t)(sn0 + r) * 256 + sg * 16;
  char* sdst = smem + wave * 1024;   // + buf*16384; gl2lds adds lane*16

  // fragment LDS offsets (row stride 64 B, swizzled slot)
  const int slot  = (q ^ ((c >> 1) & 3)) * 16;
  const int aoff0 = (wm * 32 +  0 + c) * 64 + slot;
  const int aoff1 = (wm * 32 + 16 + c) * 64 + slot;
  const int boff0 = (wn * 64 +  0 + c) * 64 + slot;
  const int boff1 = (wn * 64 + 16 + c) * 64 + slot;
  const int boff2 = (wn * 64 + 32 + c) * 64 + slot;
  const int boff3 = (wn * 64 + 48 + c) * 64 + slot;

  f32x4 accx[2][4], accy[2][4];
  #pragma unroll
  for (int i = 0; i < 2; ++i)
    #pragma unroll
    for (int j = 0; j < 4; ++j) {
      accx[i][j] = (f32x4){0.f,0.f,0.f,0.f};
      accy[i][j] = (f32x4){0.f,0.f,0.f,0.f};
    }

  // chunk kc lives in buffer kc&3; STAGE(kc+3) overwrites buf[(kc-1)&3], whose
  // readers finished before iteration kc's head barrier.
#define STAGE(kc) do {                                                      \
    const char* _sa; const char* _sb;                                       \
    if ((kc) < 8) { _sa = aXp + (kc) * 64;       _sb = bXp + (kc) * 64; }   \
    else          { _sa = aYp + ((kc) - 8) * 64; _sb = bYp + ((kc) - 8) * 64; } \
    char* _d = sdst + ((kc) & 3) * 16384;                                   \
    gl2lds16(_sa, _d);                                                      \
    gl2lds16(_sb, _d + 8192);                                               \
  } while (0)

#define MFMA8(ACC, A0, A1, B0, B1, B2, B3) do {                                   \
    ACC[0][0] = __builtin_amdgcn_mfma_f32_16x16x32_bf16(A0, B0, ACC[0][0], 0,0,0); \
    ACC[0][1] = __builtin_amdgcn_mfma_f32_16x16x32_bf16(A0, B1, ACC[0][1], 0,0,0); \
    ACC[0][2] = __builtin_amdgcn_mfma_f32_16x16x32_bf16(A0, B2, ACC[0][2], 0,0,0); \
    ACC[0][3] = __builtin_amdgcn_mfma_f32_16x16x32_bf16(A0, B3, ACC[0][3], 0,0,0); \
    ACC[1][0] = __builtin_amdgcn_mfma_f32_16x16x32_bf16(A1, B0, ACC[1][0], 0,0,0); \
    ACC[1][1] = __builtin_amdgcn_mfma_f32_16x16x32_bf16(A1, B1, ACC[1][1], 0,0,0); \
    ACC[1][2] = __builtin_amdgcn_mfma_f32_16x16x32_bf16(A1, B2, ACC[1][2], 0,0,0); \
    ACC[1][3] = __builtin_amdgcn_mfma_f32_16x16x32_bf16(A1, B3, ACC[1][3], 0,0,0); \
  } while (0)

  // vm certifies stage(kc): outstanding before wait = stages kc..min(kc+2,11).
  // kc<=9 -> 6 loads outstanding, certify oldest 2 -> vm=4; kc=10 -> vm=2; kc=11 -> 0.
#define ITER(kc, vm, ACC) do {                                              \
    asm volatile("s_waitcnt vmcnt(" #vm ")" ::: "memory");                  \
    __builtin_amdgcn_s_barrier();                                           \
    asm volatile("" ::: "memory");                                          \
    const char* _base = smem + ((kc) & 3) * 16384;                          \
    bf16x8 _A0 = *(const bf16x8*)(_base + aoff0);                           \
    bf16x8 _A1 = *(const bf16x8*)(_base + aoff1);                           \
    bf16x8 _B0 = *(const bf16x8*)(_base + 8192 + boff0);                    \
    bf16x8 _B1 = *(const bf16x8*)(_base + 8192 + boff1);                    \
    bf16x8 _B2 = *(const bf16x8*)(_base + 8192 + boff2);                    \
    bf16x8 _B3 = *(const bf16x8*)(_base + 8192 + boff3);                    \
    if ((kc) + 3 < 12) STAGE((kc) + 3);                                     \
    __builtin_amdgcn_s_setprio(1);                                          \
    MFMA8(ACC, _A0, _A1, _B0, _B1, _B2, _B3);                               \
    __builtin_amdgcn_s_setprio(0);                                          \
  } while (0)

  STAGE(0); STAGE(1); STAGE(2);          // 6 loads/thread in flight

  ITER(0, 4, accx);  ITER(1, 4, accx);  ITER(2, 4, accx);  ITER(3, 4, accx);
  ITER(4, 4, accx);  ITER(5, 4, accx);  ITER(6, 4, accx);  ITER(7, 4, accx);
  ITER(8, 4, accy);  ITER(9, 4, accy);  ITER(10, 2, accy); ITER(11, 0, accy);

#undef ITER
#undef MFMA8
#undef STAGE

  // B-buffers overlap the epilogue LDS table -> fence all waves' reads first.
  __syncthreads();

  // ---- epilogue: v = acc - 0.5*(||a||^2 + ||b||^2); max-first lse ----
  float hxv[2][4], hyv[2][4];
  #pragma unroll
  for (int i = 0; i < 2; ++i)
    #pragma unroll
    for (int rr4 = 0; rr4 < 4; ++rr4) {
      int rr = bm0 + wm * 32 + i * 16 + q * 4 + rr4;
      hxv[i][rr4] = -0.5f * nx[rr];
      hyv[i][rr4] = -0.5f * ny[rr];
    }
  float hsxv[4], hsyv[4];
  #pragma unroll
  for (int j = 0; j < 4; ++j) {
    int cc = sn0 + wn * 64 + j * 16 + c;
    hsxv[j] = -0.5f * nsx[cc];
    hsyv[j] = -0.5f * nsy[cc];
  }

  // partial table [3][128] rows of 17 float2 (136 B): pad from 16 breaks the
  // 128B-stride 4-way bank conflicts (R3's 393K conflict cycles). 52224 B < 64 KB.
  float2* xch2 = (float2*)smem;
  #pragma unroll
  for (int i = 0; i < 2; ++i) {
    #pragma unroll
    for (int rr4 = 0; rr4 < 4; ++rr4) {
      float vx[4], vy[4];
      #pragma unroll
      for (int j = 0; j < 4; ++j) {
        vx[j] = accx[i][j][rr4] + hxv[i][rr4] + hsxv[j];
        vy[j] = accy[i][j][rr4] + hyv[i][rr4] + hsyv[j];
      }
      int rl = wm * 32 + i * 16 + q * 4 + rr4;
      #pragma unroll
      for (int st = 0; st < 3; ++st) {
        float v0 = (st == 0) ? vx[0] + vy[0] : (st == 1 ? vx[0] : vy[0]);
        float v1 = (st == 0) ? vx[1] + vy[1] : (st == 1 ? vx[1] : vy[1]);
        float v2 = (st == 0) ? vx[2] + vy[2] : (st == 1 ? vx[2] : vy[2]);
        float v3 = (st == 0) ? vx[3] + vy[3] : (st == 1 ? vx[3] : vy[3]);
        float m = fmaxf(fmaxf(v0, v1), fmaxf(v2, v3));
        float s = __expf(v0 - m) + __expf(v1 - m) + __expf(v2 - m) + __expf(v3 - m);
        // merge lanes c and c^8 (both halves compute identical result)
        float mo = __shfl_xor(m, 8);
        float so = __shfl_xor(s, 8);
        float nm = fmaxf(m, mo);
        float ns = s * __expf(m - nm) + so * __expf(mo - nm);
        if (c < 8) xch2[(st * 128 + rl) * 17 + wn * 8 + c] = (float2){nm, ns};
      }
    }
  }
  __syncthreads();

  // merge the 16 lane-partials per (stream,row); write coalesced [3][64][4096]
  if (tid < 384) {
    int st = tid >> 7;
    int rl = tid & 127;
    const float2* row = xch2 + (st * 128 + rl) * 17;
    int p0 = rl & 15;                 // rotate read order: extra spread
    float2 a = row[p0];
    float m = a.x, s = a.y;
    #pragma unroll
    for (int p = 1; p < 16; ++p) {
      float2 e = row[(p0 + p) & 15];
      float nm = fmaxf(m, e.x);
      s = s * __expf(m - nm) + e.y * __expf(e.x - nm);
      m = nm;
    }
    size_t idx = ((size_t)st * 64 + sn_t) * B_N + (bm0 + rl);
    ((float2*)part)[idx] = (float2){m, s};
  }
}

// ---- finalize (fin1+fin2 fused): per-row lse over 64 partials; block sums
// combined via device-scope atomics (only 64 blocks -> 64 fences, cheap).
__global__ __launch_bounds__(256) void fin_all(const float* __restrict__ part,
                                               char* __restrict__ ws,
                                               float* __restrict__ out) {
  __shared__ float2 lds[3][4][64];
  int tid  = threadIdx.x;
  int wave = tid >> 6;
  int lane = tid & 63;
  int row  = blockIdx.x * 64 + lane;
  #pragma unroll
  for (int j = 0; j < 3; ++j) {
    float m = -__builtin_inff(), s = 0.f;
    #pragma unroll
    for (int pp = 0; pp < 16; ++pp) {
      int p = wave * 16 + pp;
      float2 a = ((const float2*)part)[((size_t)j * 64 + p) * B_N + row];
      float nm = fmaxf(m, a.x);
      s = s * __expf(m - nm) + a.y * __expf(a.x - nm);
      m = nm;
    }
    lds[j][wave][lane] = (float2){m, s};
  }
  __syncthreads();
  if (wave == 0) {
    float v[3];
    #pragma unroll
    for (int j = 0; j < 3; ++j) {
      float m = -__builtin_inff(), s = 0.f;
      #pragma unroll
      for (int u = 0; u < 4; ++u) {
        float2 a = lds[j][u][lane];
        float nm = fmaxf(m, a.x);
        s = s * __expf(m - nm) + a.y * __expf(a.x - nm);
        m = nm;
      }
      v[j] = m + __logf(s);
    }
    float local = v[0] - v[1] - v[2];
    #pragma unroll
    for (int o = 32; o > 0; o >>= 1) local += __shfl_down(local, o);
    if (lane == 0) {
      unsigned* done = (unsigned*)(ws + OFF_BSUM);
      float*    fsum = (float*)(done + 1);
      atomicAdd(fsum, local);
      __threadfence();
      unsigned old = atomicAdd(done, 1u);
      if (old == 63u) {
        __threadfence();
        float tot = atomicAdd(fsum, 0.0f);   // atomic read of completed sum
        out[0] = tot * (1.0f / (float)B_N);
      }
    }
  }
}

extern "C" void kernel_launch(void* const* d_in, const int* in_sizes, int n_in,
                              void* d_out, int out_size, void* d_ws, size_t ws_size,
                              hipStream_t stream) {
  (void)in_sizes; (void)n_in; (void)out_size; (void)ws_size;
  const float* x  = (const float*)d_in[0];
  const float* y  = (const float*)d_in[1];
  const float* xs = (const float*)d_in[2];
  const float* ys = (const float*)d_in[3];
  char* ws = (char*)d_ws;

  conv_all<<<6144, 256, 0, stream>>>(x, y, xs, ys, ws);
  mie_main<<<2048, 512, 0, stream>>>(ws, (float*)(ws + OFF_PART));
  fin_all<<<B_N / 64, 256, 0, stream>>>((const float*)(ws + OFF_PART), ws, (float*)d_out);
}

// Round 7
// 129.543 us; speedup vs baseline: 3.2722x; 1.0135x over previous
//
#include <hip/hip_runtime.h>
#include <hip/hip_bf16.h>
#include <stdint.h>

// Problem dims (fixed by setup_inputs)
#define B_N 4096
#define S_N 8192
#define KX  256
#define KY  128
// Tiling: 128x128 (batch x sample) tile per block, K fused (256 x + 128 y), BK=32
#define BM 128
#define BN 128

typedef __bf16 bf16x8 __attribute__((ext_vector_type(8)));
typedef float  f32x4  __attribute__((ext_vector_type(4)));

// ---- workspace byte offsets ----
#define OFF_XH   ((size_t)0)            // 4096*256*2 = 2 MB
#define OFF_YH   ((size_t)2097152)      // 4096*128*2 = 1 MB
#define OFF_SXH  ((size_t)3145728)      // 8192*256*2 = 4 MB
#define OFF_SYH  ((size_t)7340032)      // 8192*128*2 = 2 MB
#define OFF_NX   ((size_t)9437184)      // 4096 f32
#define OFF_NY   (OFF_NX + 16384)
#define OFF_NSX  (OFF_NY + 16384)       // 8192 f32
#define OFF_NSY  (OFF_NSX + 32768)
#define OFF_PART (OFF_NSY + 32768)      // [3][64][4096] float2 = 6.29 MB
#define OFF_BSUM (OFF_PART + (size_t)3*64*4096*2*4)   // [0]=done u32, [1]=fsum f32

__device__ __forceinline__ void gl2lds16(const void* g, void* l) {
  // async global->LDS, 16B per lane; LDS dest = wave-uniform base + lane*16
  typedef const __attribute__((address_space(1))) unsigned int* gp_t;
  typedef __attribute__((address_space(3))) unsigned int* lp_t;
  __builtin_amdgcn_global_load_lds((gp_t)g, (lp_t)l, 16, 0, 0);
}

__device__ __forceinline__ unsigned short f2bf(float f) {
  unsigned u = __builtin_bit_cast(unsigned, f);
  return (unsigned short)((u + 0x7fffu + ((u >> 16) & 1u)) >> 16);
}

// ---- preprocessing v2: fp32 -> bf16 + fp32 row norms, 4 rows/wave ILP ----
// 1536 blocks; each wave owns 4 rows, issues 4 independent loads up front
// (latency hidden 4x vs v1's single load/thread). Discriminating experiment:
// if total time drops a lot, conv_all was the hidden consumer of the ~55us
// non-mie budget; if not, that budget is fixed harness overhead.
__global__ __launch_bounds__(256) void conv_all(const float* __restrict__ x,
                                                const float* __restrict__ y,
                                                const float* __restrict__ xs,
                                                const float* __restrict__ ys,
                                                char* __restrict__ ws) {
  int b    = blockIdx.x;
  int wave = threadIdx.x >> 6;
  int lane = threadIdx.x & 63;
  if (b == 0 && threadIdx.x < 2) ((unsigned*)(ws + OFF_BSUM))[threadIdx.x] = 0u;
  const float* src; unsigned short* hi; float* nrm;
  int K, r0;
  if (b < 256) {
    src = x;  hi = (unsigned short*)(ws + OFF_XH);
    nrm = (float*)(ws + OFF_NX);  K = 256; r0 = b * 16 + wave * 4;
  } else if (b < 512) {
    src = y;  hi = (unsigned short*)(ws + OFF_YH);
    nrm = (float*)(ws + OFF_NY);  K = 128; r0 = (b - 256) * 16 + wave * 4;
  } else if (b < 1024) {
    src = xs; hi = (unsigned short*)(ws + OFF_SXH);
    nrm = (float*)(ws + OFF_NSX); K = 256; r0 = (b - 512) * 16 + wave * 4;
  } else {
    src = ys; hi = (unsigned short*)(ws + OFF_SYH);
    nrm = (float*)(ws + OFF_NSY); K = 128; r0 = (b - 1024) * 16 + wave * 4;
  }
  if (K == 256) {
    float4 v[4];
    #pragma unroll
    for (int j = 0; j < 4; ++j)
      v[j] = ((const float4*)(src + (size_t)(r0 + j) * 256))[lane];
    #pragma unroll
    for (int j = 0; j < 4; ++j) {
      float vv[4] = {v[j].x, v[j].y, v[j].z, v[j].w};
      ushort4 h4;
      unsigned short* hp = (unsigned short*)&h4;
      float acc = 0.f;
      #pragma unroll
      for (int k = 0; k < 4; ++k) {
        hp[k] = f2bf(vv[k]);
        acc = fmaf(vv[k], vv[k], acc);
      }
      ((ushort4*)(hi + (size_t)(r0 + j) * 256))[lane] = h4;
      #pragma unroll
      for (int o = 32; o > 0; o >>= 1) acc += __shfl_down(acc, o);
      if (lane == 0) nrm[r0 + j] = acc;
    }
  } else {
    float2 v[4];
    #pragma unroll
    for (int j = 0; j < 4; ++j)
      v[j] = ((const float2*)(src + (size_t)(r0 + j) * 128))[lane];
    #pragma unroll
    for (int j = 0; j < 4; ++j) {
      float vv[2] = {v[j].x, v[j].y};
      ushort2 h2;
      unsigned short* hp = (unsigned short*)&h2;
      float acc = 0.f;
      #pragma unroll
      for (int k = 0; k < 2; ++k) {
        hp[k] = f2bf(vv[k]);
        acc = fmaf(vv[k], vv[k], acc);
      }
      ((ushort2*)(hi + (size_t)(r0 + j) * 128))[lane] = h2;
      #pragma unroll
      for (int o = 32; o > 0; o >>= 1) acc += __shfl_down(acc, o);
      if (lane == 0) nrm[r0 + j] = acc;
    }
  }
}

// ---- main: fused dual-GEMM (x:K=256, y:K=128) + max-first lse epilogue ----
// 512 threads = 8 waves in 4x2: wave (wm,wn) owns rows wm*32+[0,32), cols wn*64+[0,64).
// R3-verified K-loop (61 us): both A and B staged via global_load_lds into 4x16KB
// LDS buffers (homogeneous vmcnt queue). One barrier per chunk; counted vmcnt.
// Epilogue: exact R3 (stride-16 table). R6 lesson: pad-to-17 didn't change the
// conflict count (393K = 192cy/block = negligible) and cost 4.4us -> reverted.
// NO device-scope fences in this kernel (R4 lesson).
__global__ __launch_bounds__(512, 4) void mie_main(const char* __restrict__ ws,
                                                   float* __restrict__ part) {
  __shared__ __align__(16) char smem[65536];

  const int tid  = threadIdx.x;
  const int lane = tid & 63;
  const int wave = tid >> 6;
  const int c    = lane & 15;
  const int q    = lane >> 4;
  const int wm   = wave >> 1;   // 0..3
  const int wn   = wave & 1;    // 0..1

  const int b     = blockIdx.x;
  const int xcd   = b & 7;
  const int w     = b >> 3;              // 0..255
  const int bm_t  = w & 31;              // fast: A streams, stays L2-resident
  const int sn_t  = xcd * 8 + (w >> 5);  // 0..63
  const int bm0   = bm_t * BM;
  const int sn0   = sn_t * BN;

  const char* xh  = ws + OFF_XH;
  const char* yh  = ws + OFF_YH;
  const char* sxh = ws + OFF_SXH;
  const char* syh = ws + OFF_SYH;
  const float* nx  = (const float*)(ws + OFF_NX);
  const float* ny  = (const float*)(ws + OFF_NY);
  const float* nsx = (const float*)(ws + OFF_NSX);
  const float* nsy = (const float*)(ws + OFF_NSY);

  // staging: thread tid carries granule g of row r for both A and B sides.
  const int r  = tid >> 2;
  const int sg = (tid & 3) ^ ((r >> 1) & 3);
  const char* aXp = xh  + (size_t)(bm0 + r) * 512 + sg * 16;
  const char* aYp = yh  + (size_t)(bm0 + r) * 256 + sg * 16;
  const char* bXp = sxh + (size_t)(sn0 + r) * 512 + sg * 16;
  const char* bYp = syh + (size_t)(sn0 + r) * 256 + sg * 16;
  char* sdst = smem + wave * 1024;   // + buf*16384; gl2lds adds lane*16

  // fragment LDS offsets (row stride 64 B, swizzled slot)
  const int slot  = (q ^ ((c >> 1) & 3)) * 16;
  const int aoff0 = (wm * 32 +  0 + c) * 64 + slot;
  const int aoff1 = (wm * 32 + 16 + c) * 64 + slot;
  const int boff0 = (wn * 64 +  0 + c) * 64 + slot;
  const int boff1 = (wn * 64 + 16 + c) * 64 + slot;
  const int boff2 = (wn * 64 + 32 + c) * 64 + slot;
  const int boff3 = (wn * 64 + 48 + c) * 64 + slot;

  f32x4 accx[2][4], accy[2][4];
  #pragma unroll
  for (int i = 0; i < 2; ++i)
    #pragma unroll
    for (int j = 0; j < 4; ++j) {
      accx[i][j] = (f32x4){0.f,0.f,0.f,0.f};
      accy[i][j] = (f32x4){0.f,0.f,0.f,0.f};
    }

  // chunk kc lives in buffer kc&3; STAGE(kc+3) overwrites buf[(kc-1)&3], whose
  // readers finished before iteration kc's head barrier.
#define STAGE(kc) do {                                                      \
    const char* _sa; const char* _sb;                                       \
    if ((kc) < 8) { _sa = aXp + (kc) * 64;       _sb = bXp + (kc) * 64; }   \
    else          { _sa = aYp + ((kc) - 8) * 64; _sb = bYp + ((kc) - 8) * 64; } \
    char* _d = sdst + ((kc) & 3) * 16384;                                   \
    gl2lds16(_sa, _d);                                                      \
    gl2lds16(_sb, _d + 8192);                                               \
  } while (0)

#define MFMA8(ACC, A0, A1, B0, B1, B2, B3) do {                                   \
    ACC[0][0] = __builtin_amdgcn_mfma_f32_16x16x32_bf16(A0, B0, ACC[0][0], 0,0,0); \
    ACC[0][1] = __builtin_amdgcn_mfma_f32_16x16x32_bf16(A0, B1, ACC[0][1], 0,0,0); \
    ACC[0][2] = __builtin_amdgcn_mfma_f32_16x16x32_bf16(A0, B2, ACC[0][2], 0,0,0); \
    ACC[0][3] = __builtin_amdgcn_mfma_f32_16x16x32_bf16(A0, B3, ACC[0][3], 0,0,0); \
    ACC[1][0] = __builtin_amdgcn_mfma_f32_16x16x32_bf16(A1, B0, ACC[1][0], 0,0,0); \
    ACC[1][1] = __builtin_amdgcn_mfma_f32_16x16x32_bf16(A1, B1, ACC[1][1], 0,0,0); \
    ACC[1][2] = __builtin_amdgcn_mfma_f32_16x16x32_bf16(A1, B2, ACC[1][2], 0,0,0); \
    ACC[1][3] = __builtin_amdgcn_mfma_f32_16x16x32_bf16(A1, B3, ACC[1][3], 0,0,0); \
  } while (0)

  // vm certifies stage(kc): outstanding before wait = stages kc..min(kc+2,11).
#define ITER(kc, vm, ACC) do {                                              \
    asm volatile("s_waitcnt vmcnt(" #vm ")" ::: "memory");                  \
    __builtin_amdgcn_s_barrier();                                           \
    asm volatile("" ::: "memory");                                          \
    const char* _base = smem + ((kc) & 3) * 16384;                          \
    bf16x8 _A0 = *(const bf16x8*)(_base + aoff0);                           \
    bf16x8 _A1 = *(const bf16x8*)(_base + aoff1);                           \
    bf16x8 _B0 = *(const bf16x8*)(_base + 8192 + boff0);                    \
    bf16x8 _B1 = *(const bf16x8*)(_base + 8192 + boff1);                    \
    bf16x8 _B2 = *(const bf16x8*)(_base + 8192 + boff2);                    \
    bf16x8 _B3 = *(const bf16x8*)(_base + 8192 + boff3);                    \
    if ((kc) + 3 < 12) STAGE((kc) + 3);                                     \
    __builtin_amdgcn_s_setprio(1);                                          \
    MFMA8(ACC, _A0, _A1, _B0, _B1, _B2, _B3);                               \
    __builtin_amdgcn_s_setprio(0);                                          \
  } while (0)

  STAGE(0); STAGE(1); STAGE(2);          // 6 loads/thread in flight

  ITER(0, 4, accx);  ITER(1, 4, accx);  ITER(2, 4, accx);  ITER(3, 4, accx);
  ITER(4, 4, accx);  ITER(5, 4, accx);  ITER(6, 4, accx);  ITER(7, 4, accx);
  ITER(8, 4, accy);  ITER(9, 4, accy);  ITER(10, 2, accy); ITER(11, 0, accy);

#undef ITER
#undef MFMA8
#undef STAGE

  // B-buffers overlap the epilogue LDS table -> fence all waves' reads first.
  __syncthreads();

  // ---- epilogue: v = acc - 0.5*(||a||^2 + ||b||^2); max-first lse ----
  float hxv[2][4], hyv[2][4];
  #pragma unroll
  for (int i = 0; i < 2; ++i)
    #pragma unroll
    for (int rr4 = 0; rr4 < 4; ++rr4) {
      int rr = bm0 + wm * 32 + i * 16 + q * 4 + rr4;
      hxv[i][rr4] = -0.5f * nx[rr];
      hyv[i][rr4] = -0.5f * ny[rr];
    }
  float hsxv[4], hsyv[4];
  #pragma unroll
  for (int j = 0; j < 4; ++j) {
    int cc = sn0 + wn * 64 + j * 16 + c;
    hsxv[j] = -0.5f * nsx[cc];
    hsyv[j] = -0.5f * nsy[cc];
  }

  float2* xch2 = (float2*)smem;   // [3][128][16] float2 = 48 KB
  #pragma unroll
  for (int i = 0; i < 2; ++i) {
    #pragma unroll
    for (int rr4 = 0; rr4 < 4; ++rr4) {
      float vx[4], vy[4];
      #pragma unroll
      for (int j = 0; j < 4; ++j) {
        vx[j] = accx[i][j][rr4] + hxv[i][rr4] + hsxv[j];
        vy[j] = accy[i][j][rr4] + hyv[i][rr4] + hsyv[j];
      }
      int rl = wm * 32 + i * 16 + q * 4 + rr4;
      #pragma unroll
      for (int st = 0; st < 3; ++st) {
        float v0 = (st == 0) ? vx[0] + vy[0] : (st == 1 ? vx[0] : vy[0]);
        float v1 = (st == 0) ? vx[1] + vy[1] : (st == 1 ? vx[1] : vy[1]);
        float v2 = (st == 0) ? vx[2] + vy[2] : (st == 1 ? vx[2] : vy[2]);
        float v3 = (st == 0) ? vx[3] + vy[3] : (st == 1 ? vx[3] : vy[3]);
        float m = fmaxf(fmaxf(v0, v1), fmaxf(v2, v3));
        float s = __expf(v0 - m) + __expf(v1 - m) + __expf(v2 - m) + __expf(v3 - m);
        // merge lanes c and c^8 (both halves compute identical result)
        float mo = __shfl_xor(m, 8);
        float so = __shfl_xor(s, 8);
        float nm = fmaxf(m, mo);
        float ns = s * __expf(m - nm) + so * __expf(mo - nm);
        if (c < 8) xch2[(st * 128 + rl) * 16 + wn * 8 + c] = (float2){nm, ns};
      }
    }
  }
  __syncthreads();

  // merge the 16 lane-partials per (stream,row); write coalesced [3][64][4096]
  if (tid < 384) {
    int st = tid >> 7;
    int rl = tid & 127;
    const float2* row = xch2 + (st * 128 + rl) * 16;
    int p0 = rl & 15;                 // rotate read order: breaks bank conflict
    float2 a = row[p0];
    float m = a.x, s = a.y;
    #pragma unroll
    for (int p = 1; p < 16; ++p) {
      float2 e = row[(p0 + p) & 15];
      float nm = fmaxf(m, e.x);
      s = s * __expf(m - nm) + e.y * __expf(e.x - nm);
      m = nm;
    }
    size_t idx = ((size_t)st * 64 + sn_t) * B_N + (bm0 + rl);
    ((float2*)part)[idx] = (float2){m, s};
  }
}

// ---- finalize (fin1+fin2 fused): per-row lse over 64 partials; block sums
// combined via device-scope atomics (only 64 blocks -> 64 fences, cheap).
__global__ __launch_bounds__(256) void fin_all(const float* __restrict__ part,
                                               char* __restrict__ ws,
                                               float* __restrict__ out) {
  __shared__ float2 lds[3][4][64];
  int tid  = threadIdx.x;
  int wave = tid >> 6;
  int lane = tid & 63;
  int row  = blockIdx.x * 64 + lane;
  #pragma unroll
  for (int j = 0; j < 3; ++j) {
    float m = -__builtin_inff(), s = 0.f;
    #pragma unroll
    for (int pp = 0; pp < 16; ++pp) {
      int p = wave * 16 + pp;
      float2 a = ((const float2*)part)[((size_t)j * 64 + p) * B_N + row];
      float nm = fmaxf(m, a.x);
      s = s * __expf(m - nm) + a.y * __expf(a.x - nm);
      m = nm;
    }
    lds[j][wave][lane] = (float2){m, s};
  }
  __syncthreads();
  if (wave == 0) {
    float v[3];
    #pragma unroll
    for (int j = 0; j < 3; ++j) {
      float m = -__builtin_inff(), s = 0.f;
      #pragma unroll
      for (int u = 0; u < 4; ++u) {
        float2 a = lds[j][u][lane];
        float nm = fmaxf(m, a.x);
        s = s * __expf(m - nm) + a.y * __expf(a.x - nm);
        m = nm;
      }
      v[j] = m + __logf(s);
    }
    float local = v[0] - v[1] - v[2];
    #pragma unroll
    for (int o = 32; o > 0; o >>= 1) local += __shfl_down(local, o);
    if (lane == 0) {
      unsigned* done = (unsigned*)(ws + OFF_BSUM);
      float*    fsum = (float*)(done + 1);
      atomicAdd(fsum, local);
      __threadfence();
      unsigned old = atomicAdd(done, 1u);
      if (old == 63u) {
        __threadfence();
        float tot = atomicAdd(fsum, 0.0f);   // atomic read of completed sum
        out[0] = tot * (1.0f / (float)B_N);
      }
    }
  }
}

extern "C" void kernel_launch(void* const* d_in, const int* in_sizes, int n_in,
                              void* d_out, int out_size, void* d_ws, size_t ws_size,
                              hipStream_t stream) {
  (void)in_sizes; (void)n_in; (void)out_size; (void)ws_size;
  const float* x  = (const float*)d_in[0];
  const float* y  = (const float*)d_in[1];
  const float* xs = (const float*)d_in[2];
  const float* ys = (const float*)d_in[3];
  char* ws = (char*)d_ws;

  conv_all<<<1536, 256, 0, stream>>>(x, y, xs, ys, ws);
  mie_main<<<2048, 512, 0, stream>>>(ws, (float*)(ws + OFF_PART));
  fin_all<<<B_N / 64, 256, 0, stream>>>((const float*)(ws + OFF_PART), ws, (float*)d_out);
}